// Round 1
// baseline (760.456 us; speedup 1.0000x reference)
//
#include <hip/hip_runtime.h>
#include <math.h>

// Problem constants (fixed by setup_inputs)
#define NN   5570
#define BB   16
#define CIN  35
#define DD   4
#define NJ   16        // (d,j) pairs: d in [0,4), j in [0,4)  (j: gate-o2, gate-o3, upd-o0, upd-o1)
#define COLS 256       // BB * NJ
#define G1_ROWS 5632   // NN padded to 88*64 so matmul tiles can over-read harmlessly
#define SPLITK 4
#define KSLICE 1408    // 22 tiles of 64; 4*1408 = 5632 >= NN

// workspace layout (float offsets)
#define OFF_RDEN 0
#define OFF_G1T  8192                                  // 16B-aligned, leaves room for rden
#define OFF_G0   (OFF_G1T + G1_ROWS * COLS)            // 8192 + 1441792
#define OFF_PG   (OFF_G0 + (size_t)BB * NN * NJ)       // + 1425920
// total floats = OFF_PG + SPLITK*BB*NN*NJ = 8,579,584  (~34.3 MB)

// ---------------------------------------------------------------------------
// Kernel D: rden[n] = 1 / sum_m exp(relu(E_n . E_m))
// ---------------------------------------------------------------------------
__global__ __launch_bounds__(256)
void kd_rden(const float* __restrict__ e, float* __restrict__ rden) {
    const float4* E4 = (const float4*)e;
    int tid = threadIdx.x;
    int r = tid & 31, q = tid >> 5;         // 32 rows/block, 8 m-chunks
    int n = blockIdx.x * 32 + r;
    float4 en = make_float4(0.f, 0.f, 0.f, 0.f);
    if (n < NN) en = E4[n];
    float sum = 0.f;
    for (int m = q; m < NN; m += 8) {
        float4 em = E4[m];
        float dt = en.x * em.x + en.y * em.y + en.z * em.z + en.w * em.w;
        sum += __expf(fmaxf(dt, 0.f));
    }
    __shared__ float red[8][32];
    red[q][r] = sum;
    __syncthreads();
    if (tid < 32) {
        float s = 0.f;
        #pragma unroll
        for (int i = 0; i < 8; ++i) s += red[i][tid];
        int n2 = blockIdx.x * 32 + tid;
        if (n2 < NN) rden[n2] = 1.f / s;
    }
}

// ---------------------------------------------------------------------------
// Kernel G: G1T[m][b*16 + (d*4+j)] = sum_c x[b,m,c] * w_k1[d,c,j]
//           G0[b][m][d*4+j]        = sum_c x[b,m,c] * w_k0[d,c,j]
// j=0,1 -> w_gate[d,k,c,2+j] ; j=2,3 -> w_update[d,k,c,j-2]
// block = 128 threads, each handles rows m0+tid and m0+tid+128 (256 rows/block)
// ---------------------------------------------------------------------------
__global__ __launch_bounds__(128)
void kg_g(const float* __restrict__ x, const float* __restrict__ wg,
          const float* __restrict__ wu, float* __restrict__ g0,
          float* __restrict__ g1t) {
    __shared__ float xs[256 * CIN];
    __shared__ float wl[8 * CIN * 4];   // [(k*4+d)*35 + c]*4 + j
    int tid = threadIdx.x;
    int b   = blockIdx.y;
    int m0  = blockIdx.x * 256;

    for (int i = tid; i < 8 * CIN * 4; i += 128) {
        int j = i & 3, rest = i >> 2;
        int c = rest % CIN, kd = rest / CIN;
        int k = kd >> 2, d = kd & 3;
        float v;
        if (j < 2) v = wg[((d * 2 + k) * 37 + c) * 4 + 2 + j];
        else       v = wu[((d * 2 + k) * 37 + c) * 2 + (j - 2)];
        wl[i] = v;
    }
    int rows = NN - m0; if (rows > 256) rows = 256;
    const float* xsrc = x + ((size_t)b * NN + m0) * CIN;
    for (int i = tid; i < rows * CIN; i += 128) xs[i] = xsrc[i];
    __syncthreads();

    float a0a[16], a1a[16], a0b[16], a1b[16];
    #pragma unroll
    for (int i = 0; i < 16; ++i) { a0a[i] = 0.f; a1a[i] = 0.f; a0b[i] = 0.f; a1b[i] = 0.f; }

    for (int c = 0; c < CIN; ++c) {
        float xa = xs[tid * CIN + c];
        float xb = xs[(tid + 128) * CIN + c];
        #pragma unroll
        for (int kd = 0; kd < 8; ++kd) {
            const float4 w = *(const float4*)&wl[(kd * CIN + c) * 4];
            const int d4 = (kd & 3) * 4;
            if (kd < 4) {
                a0a[d4+0] += xa*w.x; a0a[d4+1] += xa*w.y; a0a[d4+2] += xa*w.z; a0a[d4+3] += xa*w.w;
                a0b[d4+0] += xb*w.x; a0b[d4+1] += xb*w.y; a0b[d4+2] += xb*w.z; a0b[d4+3] += xb*w.w;
            } else {
                a1a[d4+0] += xa*w.x; a1a[d4+1] += xa*w.y; a1a[d4+2] += xa*w.z; a1a[d4+3] += xa*w.w;
                a1b[d4+0] += xb*w.x; a1b[d4+1] += xb*w.y; a1b[d4+2] += xb*w.z; a1b[d4+3] += xb*w.w;
            }
        }
    }

    int ma = m0 + tid, mb = m0 + tid + 128;
    if (ma < NN) {
        float* p0 = g0 + ((size_t)b * NN + ma) * NJ;
        ((float4*)p0)[0] = make_float4(a0a[0], a0a[1], a0a[2], a0a[3]);
        ((float4*)p0)[1] = make_float4(a0a[4], a0a[5], a0a[6], a0a[7]);
        ((float4*)p0)[2] = make_float4(a0a[8], a0a[9], a0a[10], a0a[11]);
        ((float4*)p0)[3] = make_float4(a0a[12], a0a[13], a0a[14], a0a[15]);
        float* p1 = g1t + (size_t)ma * COLS + b * NJ;
        ((float4*)p1)[0] = make_float4(a1a[0], a1a[1], a1a[2], a1a[3]);
        ((float4*)p1)[1] = make_float4(a1a[4], a1a[5], a1a[6], a1a[7]);
        ((float4*)p1)[2] = make_float4(a1a[8], a1a[9], a1a[10], a1a[11]);
        ((float4*)p1)[3] = make_float4(a1a[12], a1a[13], a1a[14], a1a[15]);
    }
    if (mb < NN) {
        float* p0 = g0 + ((size_t)b * NN + mb) * NJ;
        ((float4*)p0)[0] = make_float4(a0b[0], a0b[1], a0b[2], a0b[3]);
        ((float4*)p0)[1] = make_float4(a0b[4], a0b[5], a0b[6], a0b[7]);
        ((float4*)p0)[2] = make_float4(a0b[8], a0b[9], a0b[10], a0b[11]);
        ((float4*)p0)[3] = make_float4(a0b[12], a0b[13], a0b[14], a0b[15]);
        float* p1 = g1t + (size_t)mb * COLS + b * NJ;
        ((float4*)p1)[0] = make_float4(a1b[0], a1b[1], a1b[2], a1b[3]);
        ((float4*)p1)[1] = make_float4(a1b[4], a1b[5], a1b[6], a1b[7]);
        ((float4*)p1)[2] = make_float4(a1b[8], a1b[9], a1b[10], a1b[11]);
        ((float4*)p1)[3] = make_float4(a1b[12], a1b[13], a1b[14], a1b[15]);
    }
}

// ---------------------------------------------------------------------------
// Kernel B: PG[slice][b][n][dj] = sum_{m in slice} exp(relu(E_n.E_m)) * G1T[m][b*16+dj]
// 64 rows x 256 cols per block; thread tile = 8 rows x 8 cols (64 fp32 acc)
// ---------------------------------------------------------------------------
__global__ __launch_bounds__(256)
void kb_pg(const float* __restrict__ e, const float* __restrict__ g1t,
           float* __restrict__ pg) {
    __shared__ float4 enl[64];
    __shared__ float4 eml[64];
    __shared__ float  ss[64 * 64];     // ss[mi][tn]
    int tid = threadIdx.x;
    int n0 = blockIdx.x * 64;
    int k0 = blockIdx.y * KSLICE;
    int k1 = k0 + KSLICE; if (k1 > NN) k1 = NN;
    const float4* E4 = (const float4*)e;
    const float4 z4 = make_float4(0.f, 0.f, 0.f, 0.f);

    if (tid < 64) { int n = n0 + tid; enl[tid] = (n < NN) ? E4[n] : z4; }
    __syncthreads();

    const int lane63 = tid & 63;
    const int sub    = tid >> 6;       // 0..3 (which quarter of mi)
    const float4 enm = enl[lane63];
    const int cg = tid & 31;           // col group: cols cg*8 .. cg*8+7
    const int tg = tid >> 5;           // row group: rows tg*8 .. tg*8+7

    float acc[8][8];
    #pragma unroll
    for (int i = 0; i < 8; ++i)
        #pragma unroll
        for (int j = 0; j < 8; ++j) acc[i][j] = 0.f;

    for (int m0 = k0; m0 < k0 + KSLICE; m0 += 64) {
        __syncthreads();
        if (tid < 64) { int m = m0 + tid; eml[tid] = (m < NN) ? E4[m] : z4; }
        __syncthreads();
        #pragma unroll
        for (int u = 0; u < 16; ++u) {
            int mi = u * 4 + sub;
            float4 emv = eml[mi];
            float dt = enm.x * emv.x + enm.y * emv.y + enm.z * emv.z + enm.w * emv.w;
            float s = 0.f;
            if (m0 + mi < k1) s = __expf(fmaxf(dt, 0.f));
            ss[mi * 64 + lane63] = s;
        }
        __syncthreads();

        const float* gb = g1t + (size_t)m0 * COLS + cg * 8;
        #pragma unroll 2
        for (int mi = 0; mi < 64; ++mi) {
            float4 ga  = *(const float4*)(gb + (size_t)mi * COLS);
            float4 gc  = *(const float4*)(gb + (size_t)mi * COLS + 4);
            const float4* sp = (const float4*)&ss[mi * 64 + tg * 8];
            float4 sa = sp[0], sb = sp[1];
            float s8[8] = {sa.x, sa.y, sa.z, sa.w, sb.x, sb.y, sb.z, sb.w};
            float g8[8] = {ga.x, ga.y, ga.z, ga.w, gc.x, gc.y, gc.z, gc.w};
            #pragma unroll
            for (int i = 0; i < 8; ++i)
                #pragma unroll
                for (int j = 0; j < 8; ++j)
                    acc[i][j] += s8[i] * g8[j];
        }
    }

    // store: col = cg*8 + j  ->  b = col>>4, dj = col&15 (8-aligned, no b-straddle)
    int bcol = cg >> 1;
    int djb  = (cg & 1) * 8;
    size_t sbase = (size_t)blockIdx.y * BB * NN * NJ;
    #pragma unroll
    for (int ti = 0; ti < 8; ++ti) {
        int n = n0 + tg * 8 + ti;
        if (n < NN) {
            float* p = pg + sbase + ((size_t)bcol * NN + n) * NJ + djb;
            ((float4*)p)[0] = make_float4(acc[ti][0], acc[ti][1], acc[ti][2], acc[ti][3]);
            ((float4*)p)[1] = make_float4(acc[ti][4], acc[ti][5], acc[ti][6], acc[ti][7]);
        }
    }
}

// ---------------------------------------------------------------------------
// Kernel E: epilogue
// pre[j] = sum_d E[n,d]*(G0[b,n,d*4+j]) + rden[n]*sum_d E[n,d]*PGsum[b,n,d*4+j] + bias_j
// R=sigmoid(pre[0..1]), C=tanh(pre[2..3]), h=(1-R)*C, y = relu(h)@lin_w + lin_b
// ---------------------------------------------------------------------------
__global__ __launch_bounds__(256)
void ke_out(const float* __restrict__ e, const float* __restrict__ rden,
            const float* __restrict__ g0, const float* __restrict__ pg,
            const float* __restrict__ bg, const float* __restrict__ bu,
            const float* __restrict__ lw, const float* __restrict__ lb,
            float* __restrict__ out) {
    int n = blockIdx.x * 256 + threadIdx.x;
    int b = blockIdx.y;
    if (n >= NN) return;
    const float4* E4 = (const float4*)e;
    float4 ev = E4[n];
    float ed[4] = {ev.x, ev.y, ev.z, ev.w};
    float rd = rden[n];
    size_t base = ((size_t)b * NN + n) * NJ;

    float g0f[16];
    #pragma unroll
    for (int i = 0; i < 4; ++i) {
        float4 t = *(const float4*)(g0 + base + i * 4);
        g0f[i*4+0] = t.x; g0f[i*4+1] = t.y; g0f[i*4+2] = t.z; g0f[i*4+3] = t.w;
    }
    float pgf[16];
    #pragma unroll
    for (int i = 0; i < 16; ++i) pgf[i] = 0.f;
    #pragma unroll
    for (int s2 = 0; s2 < SPLITK; ++s2) {
        const float* sp = pg + (size_t)s2 * BB * NN * NJ + base;
        #pragma unroll
        for (int i = 0; i < 4; ++i) {
            float4 t = *(const float4*)(sp + i * 4);
            pgf[i*4+0] += t.x; pgf[i*4+1] += t.y; pgf[i*4+2] += t.z; pgf[i*4+3] += t.w;
        }
    }

    float pre[4];
    #pragma unroll
    for (int j = 0; j < 4; ++j) {
        float t0 = 0.f, t1 = 0.f, bj = 0.f;
        #pragma unroll
        for (int d = 0; d < 4; ++d) {
            t0 += ed[d] * g0f[d*4+j];
            t1 += ed[d] * pgf[d*4+j];
            float bp = (j < 2) ? bg[d * 4 + 2 + j] : bu[d * 2 + (j - 2)];
            bj += ed[d] * bp;
        }
        pre[j] = t0 + rd * t1 + bj;
    }
    float R0 = 1.f / (1.f + __expf(-pre[0]));
    float R1 = 1.f / (1.f + __expf(-pre[1]));
    float C0 = tanhf(pre[2]);
    float C1 = tanhf(pre[3]);
    float h0 = (1.f - R0) * C0;
    float h1 = (1.f - R1) * C1;
    float y = fmaxf(h0, 0.f) * lw[0] + fmaxf(h1, 0.f) * lw[1] + lb[0];
    out[(size_t)b * NN + n] = y;
}

// ---------------------------------------------------------------------------
extern "C" void kernel_launch(void* const* d_in, const int* in_sizes, int n_in,
                              void* d_out, int out_size, void* d_ws, size_t ws_size,
                              hipStream_t stream) {
    const float* x  = (const float*)d_in[0];
    const float* e  = (const float*)d_in[1];
    const float* wg = (const float*)d_in[2];
    const float* bg = (const float*)d_in[3];
    const float* wu = (const float*)d_in[4];
    const float* bu = (const float*)d_in[5];
    const float* lw = (const float*)d_in[6];
    const float* lb = (const float*)d_in[7];
    float* out = (float*)d_out;

    float* wsf  = (float*)d_ws;
    float* rden = wsf + OFF_RDEN;
    float* g1t  = wsf + OFF_G1T;
    float* g0   = wsf + OFF_G0;
    float* pg   = wsf + OFF_PG;

    hipLaunchKernelGGL(kd_rden, dim3(175), dim3(256), 0, stream, e, rden);
    hipLaunchKernelGGL(kg_g, dim3(22, 16), dim3(128), 0, stream, x, wg, wu, g0, g1t);
    hipLaunchKernelGGL(kb_pg, dim3(88, SPLITK), dim3(256), 0, stream, e, g1t, pg);
    hipLaunchKernelGGL(ke_out, dim3(22, 16), dim3(256), 0, stream,
                       e, rden, g0, pg, bg, bu, lw, lb, out);
}

// Round 2
// 179.437 us; speedup vs baseline: 4.2380x; 4.2380x over previous
//
#include <hip/hip_runtime.h>
#include <hip/hip_bf16.h>
#include <math.h>

// Problem constants (fixed by setup_inputs)
#define NN   5570
#define BB   16
#define CIN  35
#define NJ   16        // (d,j) pairs: d in [0,4), j in [0,4)  (j: gate-o2, gate-o3, upd-o0, upd-o1)
#define COLS 256       // BB * NJ
#define MPAD 5632      // NN padded to 88*64
#define SPLITK 4
#define KSLICE 1408    // 22 chunks of 64; 4*1408 = 5632
#define MT   32        // n-rows per block in kb_pg

// workspace layout (float offsets)
#define OFF_RSUM 0                                     // [SPLITK][MPAD] fp32 = 22528
#define OFF_G0   22528                                 // [BB][NN][NJ] fp32 = 1425920
#define OFF_PG   (OFF_G0 + (size_t)BB * NN * NJ)       // [SPLITK][BB][NN][NJ] fp32
#define OFF_GT_F (OFF_PG + (size_t)SPLITK * BB * NN * NJ)  // GT bf16 [COLS][MPAD] after this
// total bytes = OFF_GT_F*4 + COLS*MPAD*2 = 31,492,096 (~30 MB)

typedef __attribute__((ext_vector_type(8))) short  short8;
typedef __attribute__((ext_vector_type(4))) float  floatx4;

static __device__ inline ushort f2bf(float f) {
    union { __hip_bfloat16 h; ushort u; } cv;
    cv.h = __float2bfloat16(f);
    return cv.u;
}

// ---------------------------------------------------------------------------
// Kernel G: per (b, m):
//   a0[dj] = sum_c x[b,m,c] * w_k0[d,c,j]  -> g0   fp32 [b][m][16]
//   a1[dj] = sum_c x[b,m,c] * w_k1[d,c,j]  -> GT   bf16 [b*16+dj][m]   (transposed!)
// tail m in [NN, MPAD): GT <- 0
// ---------------------------------------------------------------------------
__global__ __launch_bounds__(128)
void kg_g(const float* __restrict__ x, const float* __restrict__ wg,
          const float* __restrict__ wu, float* __restrict__ g0,
          ushort* __restrict__ gtu) {
    __shared__ float xs[256 * CIN];
    __shared__ float wl[8 * CIN * 4];   // [(k*4+d)*35 + c]*4 + j
    int tid = threadIdx.x;
    int b   = blockIdx.y;
    int m0  = blockIdx.x * 256;

    for (int i = tid; i < 8 * CIN * 4; i += 128) {
        int j = i & 3, rest = i >> 2;
        int c = rest % CIN, kd = rest / CIN;
        int k = kd >> 2, d = kd & 3;
        float v;
        if (j < 2) v = wg[((d * 2 + k) * 37 + c) * 4 + 2 + j];
        else       v = wu[((d * 2 + k) * 37 + c) * 2 + (j - 2)];
        wl[i] = v;
    }
    int rows = NN - m0; if (rows > 256) rows = 256; if (rows < 0) rows = 0;
    const float* xsrc = x + ((size_t)b * NN + m0) * CIN;
    for (int i = tid; i < rows * CIN; i += 128) xs[i] = xsrc[i];
    __syncthreads();

    float a0a[16], a1a[16], a0b[16], a1b[16];
    #pragma unroll
    for (int i = 0; i < 16; ++i) { a0a[i] = 0.f; a1a[i] = 0.f; a0b[i] = 0.f; a1b[i] = 0.f; }

    for (int c = 0; c < CIN; ++c) {
        float xa = xs[tid * CIN + c];
        float xb = xs[(tid + 128) * CIN + c];
        #pragma unroll
        for (int kd = 0; kd < 8; ++kd) {
            const float4 w = *(const float4*)&wl[(kd * CIN + c) * 4];
            const int d4 = (kd & 3) * 4;
            if (kd < 4) {
                a0a[d4+0] += xa*w.x; a0a[d4+1] += xa*w.y; a0a[d4+2] += xa*w.z; a0a[d4+3] += xa*w.w;
                a0b[d4+0] += xb*w.x; a0b[d4+1] += xb*w.y; a0b[d4+2] += xb*w.z; a0b[d4+3] += xb*w.w;
            } else {
                a1a[d4+0] += xa*w.x; a1a[d4+1] += xa*w.y; a1a[d4+2] += xa*w.z; a1a[d4+3] += xa*w.w;
                a1b[d4+0] += xb*w.x; a1b[d4+1] += xb*w.y; a1b[d4+2] += xb*w.z; a1b[d4+3] += xb*w.w;
            }
        }
    }

    int ma = m0 + tid, mb = m0 + tid + 128;
    // row ma
    if (ma < NN) {
        float* p0 = g0 + ((size_t)b * NN + ma) * NJ;
        ((float4*)p0)[0] = make_float4(a0a[0], a0a[1], a0a[2], a0a[3]);
        ((float4*)p0)[1] = make_float4(a0a[4], a0a[5], a0a[6], a0a[7]);
        ((float4*)p0)[2] = make_float4(a0a[8], a0a[9], a0a[10], a0a[11]);
        ((float4*)p0)[3] = make_float4(a0a[12], a0a[13], a0a[14], a0a[15]);
        #pragma unroll
        for (int dj = 0; dj < 16; ++dj)
            gtu[(size_t)(b * 16 + dj) * MPAD + ma] = f2bf(a1a[dj]);
    } else {
        #pragma unroll
        for (int dj = 0; dj < 16; ++dj)
            gtu[(size_t)(b * 16 + dj) * MPAD + ma] = 0;
    }
    // row mb
    if (mb < NN) {
        float* p0 = g0 + ((size_t)b * NN + mb) * NJ;
        ((float4*)p0)[0] = make_float4(a0b[0], a0b[1], a0b[2], a0b[3]);
        ((float4*)p0)[1] = make_float4(a0b[4], a0b[5], a0b[6], a0b[7]);
        ((float4*)p0)[2] = make_float4(a0b[8], a0b[9], a0b[10], a0b[11]);
        ((float4*)p0)[3] = make_float4(a0b[12], a0b[13], a0b[14], a0b[15]);
        #pragma unroll
        for (int dj = 0; dj < 16; ++dj)
            gtu[(size_t)(b * 16 + dj) * MPAD + mb] = f2bf(a1b[dj]);
    } else {
        #pragma unroll
        for (int dj = 0; dj < 16; ++dj)
            gtu[(size_t)(b * 16 + dj) * MPAD + mb] = 0;
    }
}

// ---------------------------------------------------------------------------
// Kernel B (MFMA): PG[s][b][n][dj] = sum_{m in slice s} exp(relu(E_n.E_m)) * G1[m][b*16+dj]
// Also rsum[s][n] = sum_{m in slice s} exp(relu(E_n.E_m))  (fp32, for 1/den)
// Block: 256 thr (4 waves) = 32 rows x 256 cols; K-chunk 64 = 2 MFMA k-tiles.
// Scores packed bf16 into LDS [32][72] (pad 8 -> even bank spread).
// Wave w handles cols w*64..w*64+63 (4 col-tiles of 16); 2 row-tiles of 16.
// ---------------------------------------------------------------------------
__global__ __launch_bounds__(256)
void kb_pg(const float* __restrict__ e, const ushort* __restrict__ gtu,
           float* __restrict__ pg, float* __restrict__ rsum) {
    __shared__ ushort ssb[MT * 72];      // 4608 B
    __shared__ float rred[4][32];

    const int tid  = threadIdx.x;
    const int wave = tid >> 6;
    const int lane = tid & 63;
    const int l15  = lane & 15;
    const int quad = lane >> 4;
    const int n0   = blockIdx.x * MT;
    const int s    = blockIdx.y;
    const int k0   = s * KSLICE;

    // score-gen assignment: row r = tid&31 (shared by 8 threads), k-group kg = tid>>5
    const int r  = tid & 31;
    const int kg = tid >> 5;
    const float4* E4 = (const float4*)e;
    const int nr = n0 + r;
    const float4 en = E4[nr < NN ? nr : (NN - 1)];

    float rowsum = 0.f;
    floatx4 acc[2][4];
    #pragma unroll
    for (int i = 0; i < 2; ++i)
        #pragma unroll
        for (int j = 0; j < 4; ++j)
            acc[i][j] = (floatx4){0.f, 0.f, 0.f, 0.f};

    const ushort* gw = gtu + (size_t)(wave * 64) * MPAD;

    for (int chunk = 0; chunk < KSLICE / 64; ++chunk) {
        const int m_base = k0 + chunk * 64;
        // ---- score phase: 8 scores per thread (row r, m = m_base + kg*8 + u)
        float sc[8];
        const int mge = m_base + kg * 8;
        #pragma unroll
        for (int u = 0; u < 8; ++u) {
            int m = mge + u;
            float4 em = E4[m < NN ? m : 0];
            float dt = en.x * em.x + en.y * em.y + en.z * em.z + en.w * em.w;
            float sv = (m < NN) ? __expf(fmaxf(dt, 0.f)) : 0.f;
            rowsum += sv;
            sc[u] = sv;
        }
        short8 pk;
        #pragma unroll
        for (int u = 0; u < 8; ++u) pk[u] = (short)f2bf(sc[u]);

        __syncthreads();   // prev chunk's MFMA reads of ssb are done
        *(short8*)&ssb[r * 72 + kg * 8] = pk;
        __syncthreads();   // scores visible

        // ---- MFMA phase: 2 k-tiles x (2 row-tiles x 4 col-tiles)
        #pragma unroll
        for (int kt = 0; kt < 2; ++kt) {
            const int koff = kt * 32 + quad * 8;
            short8 a0 = *(const short8*)&ssb[l15 * 72 + koff];
            short8 a1 = *(const short8*)&ssb[(16 + l15) * 72 + koff];
            #pragma unroll
            for (int ct = 0; ct < 4; ++ct) {
                short8 bf = *(const short8*)&gw[(size_t)(ct * 16 + l15) * MPAD + m_base + koff];
                acc[0][ct] = __builtin_amdgcn_mfma_f32_16x16x32_bf16(a0, bf, acc[0][ct], 0, 0, 0);
                acc[1][ct] = __builtin_amdgcn_mfma_f32_16x16x32_bf16(a1, bf, acc[1][ct], 0, 0, 0);
            }
        }
    }

    // ---- rsum reduce: lanes l and l^32 share row r
    rowsum += __shfl_xor(rowsum, 32);
    if (lane < 32) rred[wave][lane] = rowsum;
    __syncthreads();
    if (tid < 32) {
        float tot = rred[0][tid] + rred[1][tid] + rred[2][tid] + rred[3][tid];
        int n = n0 + tid;
        if (n < NN) rsum[(size_t)s * MPAD + n] = tot;
    }

    // ---- PG stores: D[row][col], row=(quad*4+reg), col=l15 within each 16x16 tile
    #pragma unroll
    for (int rt = 0; rt < 2; ++rt) {
        #pragma unroll
        for (int ct = 0; ct < 4; ++ct) {
            int bcol = wave * 4 + ct;
            float* dst = pg + ((size_t)s * BB + bcol) * NN * NJ;
            #pragma unroll
            for (int j = 0; j < 4; ++j) {
                int n = n0 + rt * 16 + quad * 4 + j;
                if (n < NN) dst[(size_t)n * NJ + l15] = acc[rt][ct][j];
            }
        }
    }
}

// ---------------------------------------------------------------------------
// Kernel E: epilogue
// pre[j] = sum_d E[n,d]*G0[b,n,dj] + (1/sum_s rsum[s][n]) * sum_d E[n,d]*PGsum + bias
// R=sigmoid(pre[0..1]), C=tanh(pre[2..3]), h=(1-R)*C, y = relu(h)@lin_w + lin_b
// ---------------------------------------------------------------------------
__global__ __launch_bounds__(256)
void ke_out(const float* __restrict__ e, const float* __restrict__ rsum,
            const float* __restrict__ g0, const float* __restrict__ pg,
            const float* __restrict__ bg, const float* __restrict__ bu,
            const float* __restrict__ lw, const float* __restrict__ lb,
            float* __restrict__ out) {
    int n = blockIdx.x * 256 + threadIdx.x;
    int b = blockIdx.y;
    if (n >= NN) return;
    const float4* E4 = (const float4*)e;
    float4 ev = E4[n];
    float ed[4] = {ev.x, ev.y, ev.z, ev.w};
    float rd = 1.f / (rsum[n] + rsum[MPAD + n] + rsum[2 * MPAD + n] + rsum[3 * MPAD + n]);
    size_t base = ((size_t)b * NN + n) * NJ;

    float g0f[16];
    #pragma unroll
    for (int i = 0; i < 4; ++i) {
        float4 t = *(const float4*)(g0 + base + i * 4);
        g0f[i*4+0] = t.x; g0f[i*4+1] = t.y; g0f[i*4+2] = t.z; g0f[i*4+3] = t.w;
    }
    float pgf[16];
    #pragma unroll
    for (int i = 0; i < 16; ++i) pgf[i] = 0.f;
    #pragma unroll
    for (int s2 = 0; s2 < SPLITK; ++s2) {
        const float* sp = pg + (size_t)s2 * BB * NN * NJ + base;
        #pragma unroll
        for (int i = 0; i < 4; ++i) {
            float4 t = *(const float4*)(sp + i * 4);
            pgf[i*4+0] += t.x; pgf[i*4+1] += t.y; pgf[i*4+2] += t.z; pgf[i*4+3] += t.w;
        }
    }

    float pre[4];
    #pragma unroll
    for (int j = 0; j < 4; ++j) {
        float t0 = 0.f, t1 = 0.f, bj = 0.f;
        #pragma unroll
        for (int d = 0; d < 4; ++d) {
            t0 += ed[d] * g0f[d*4+j];
            t1 += ed[d] * pgf[d*4+j];
            float bp = (j < 2) ? bg[d * 4 + 2 + j] : bu[d * 2 + (j - 2)];
            bj += ed[d] * bp;
        }
        pre[j] = t0 + rd * t1 + bj;
    }
    float R0 = 1.f / (1.f + __expf(-pre[0]));
    float R1 = 1.f / (1.f + __expf(-pre[1]));
    float C0 = tanhf(pre[2]);
    float C1 = tanhf(pre[3]);
    float h0 = (1.f - R0) * C0;
    float h1 = (1.f - R1) * C1;
    float y = fmaxf(h0, 0.f) * lw[0] + fmaxf(h1, 0.f) * lw[1] + lb[0];
    out[(size_t)b * NN + n] = y;
}

// ---------------------------------------------------------------------------
extern "C" void kernel_launch(void* const* d_in, const int* in_sizes, int n_in,
                              void* d_out, int out_size, void* d_ws, size_t ws_size,
                              hipStream_t stream) {
    const float* x  = (const float*)d_in[0];
    const float* e  = (const float*)d_in[1];
    const float* wg = (const float*)d_in[2];
    const float* bg = (const float*)d_in[3];
    const float* wu = (const float*)d_in[4];
    const float* bu = (const float*)d_in[5];
    const float* lw = (const float*)d_in[6];
    const float* lb = (const float*)d_in[7];
    float* out = (float*)d_out;

    float*  wsf  = (float*)d_ws;
    float*  rsum = wsf + OFF_RSUM;
    float*  g0   = wsf + OFF_G0;
    float*  pg   = wsf + OFF_PG;
    ushort* gtu  = (ushort*)(wsf + OFF_GT_F);

    hipLaunchKernelGGL(kg_g, dim3(22, 16), dim3(128), 0, stream, x, wg, wu, g0, gtu);
    hipLaunchKernelGGL(kb_pg, dim3(MPAD / MT, SPLITK), dim3(256), 0, stream, e, gtu, pg, rsum);
    hipLaunchKernelGGL(ke_out, dim3(22, 16), dim3(256), 0, stream,
                       e, rsum, g0, pg, bg, bu, lw, lb, out);
}